// Round 1
// baseline (144.040 us; speedup 1.0000x reference)
//
#include <hip/hip_runtime.h>
#include <math.h>

// Problem constants (B=1, C=64, H=W=256, N=4096, T=0.1)
#define HW2     65536      // H*W
#define NLOC    4096       // N
#define NROW    8192       // 2N rows in the Gram matrix
#define CDIM    64         // channels
#define TINV    10.0f      // 1/T
#define EXP10   22026.465794806718f   // exp(1/T)
#define JCHUNKS 8
#define JCHUNK  1024       // NROW / JCHUNKS

// ---------------------------------------------------------------------------
// Kernel 1: gather G[i][c] = emb_{0|1}[c][ind(i)], i in [0, 8192)
// ---------------------------------------------------------------------------
__global__ __launch_bounds__(256) void gather_kernel(
    const float* __restrict__ emb0, const float* __restrict__ emb1,
    const float* __restrict__ loc0, const float* __restrict__ loc1,
    float* __restrict__ G) {
  int t = blockIdx.x * 256 + threadIdx.x;   // 0 .. NROW*CDIM
  int i = t >> 6;
  int c = t & 63;
  const float* loc = (i < NLOC) ? loc0 : loc1;
  const float* emb = (i < NLOC) ? emb0 : emb1;
  int u = (i < NLOC) ? i : (i - NLOC);
  int ind = (int)floorf(loc[u * 2]) * 256 + (int)floorf(loc[u * 2 + 1]);
  G[(size_t)i * CDIM + c] = emb[(size_t)c * HW2 + ind];
}

// ---------------------------------------------------------------------------
// Kernel 2: for each row i, accumulate sum_j exp(10 * g_i . g_j) over a
// 1024-column chunk; also accumulate sim[u, u+4096] band terms.
// Block: 256 threads = 16(ti) x 16(tj); 64-row i-tile, 16 j-tiles of 64.
// LDS tiles stored TRANSPOSED: At[k][i_local] so inner loop is float4
// contiguous reads (A: 2-way free aliasing, B: 16-lane broadcast).
// ---------------------------------------------------------------------------
__global__ __launch_bounds__(256) void simsum_kernel(
    const float* __restrict__ G, float* __restrict__ rowPart,
    float* __restrict__ crossPart) {
  __shared__ float At[64][64];
  __shared__ float Bt[64][64];
  __shared__ float red[64][17];
  __shared__ float credA[256];

  const int tid = threadIdx.x;
  const int i0 = blockIdx.x * 64;
  const int j0 = blockIdx.y * JCHUNK;

  // Stage A tile transposed: At[k][il] = G[i0+il][k]
  {
    const int row = tid & 63;   // i_local
    const int kg  = tid >> 6;   // 0..3 -> k = kg*16 .. kg*16+15
    const float4* src =
        reinterpret_cast<const float4*>(G + (size_t)(i0 + row) * CDIM + kg * 16);
    float4 v[4];
    v[0] = src[0]; v[1] = src[1]; v[2] = src[2]; v[3] = src[3];
    const float* vf = reinterpret_cast<const float*>(v);
#pragma unroll
    for (int e = 0; e < 16; ++e) At[kg * 16 + e][row] = vf[e];
  }

  const int ti = tid & 15;
  const int tj = tid >> 4;
  float accExp[4] = {0.f, 0.f, 0.f, 0.f};
  float cross = 0.f;

  for (int jt = 0; jt < JCHUNK / 64; ++jt) {
    __syncthreads();  // A staged (jt==0) / previous Bt reads done
    {
      const int row = tid & 63;
      const int kg  = tid >> 6;
      const float4* src = reinterpret_cast<const float4*>(
          G + (size_t)(j0 + jt * 64 + row) * CDIM + kg * 16);
      float4 v[4];
      v[0] = src[0]; v[1] = src[1]; v[2] = src[2]; v[3] = src[3];
      const float* vf = reinterpret_cast<const float*>(v);
#pragma unroll
      for (int e = 0; e < 16; ++e) Bt[kg * 16 + e][row] = vf[e];
    }
    __syncthreads();

    float acc[4][4];
#pragma unroll
    for (int r = 0; r < 4; ++r)
#pragma unroll
      for (int s = 0; s < 4; ++s) acc[r][s] = 0.f;

#pragma unroll 8
    for (int k = 0; k < 64; ++k) {
      float4 a = *reinterpret_cast<const float4*>(&At[k][ti * 4]);
      float4 b = *reinterpret_cast<const float4*>(&Bt[k][tj * 4]);
      const float af[4] = {a.x, a.y, a.z, a.w};
      const float bf[4] = {b.x, b.y, b.z, b.w};
#pragma unroll
      for (int r = 0; r < 4; ++r)
#pragma unroll
        for (int s = 0; s < 4; ++s) acc[r][s] += af[r] * bf[s];
    }

    // epilogue: exp + row-partial accumulate + diagonal-band extraction
#pragma unroll
    for (int r = 0; r < 4; ++r) {
      const int ig = i0 + ti * 4 + r;
#pragma unroll
      for (int s = 0; s < 4; ++s) {
        const int jg = j0 + jt * 64 + tj * 4 + s;
        const float sim = acc[r][s];
        accExp[r] += __expf(sim * TINV);
        if (jg == ig + NLOC) cross += sim;
      }
    }
  }

  // deterministic block reductions
  __syncthreads();
#pragma unroll
  for (int r = 0; r < 4; ++r) red[ti * 4 + r][tj] = accExp[r];
  credA[tid] = cross;
  __syncthreads();

  if (tid < 64) {
    float s = 0.f;
#pragma unroll
    for (int q = 0; q < 16; ++q) s += red[tid][q];
    rowPart[(size_t)(i0 + tid) * JCHUNKS + blockIdx.y] = s;
  }
  for (int s = 128; s > 0; s >>= 1) {
    if (tid < s) credA[tid] += credA[tid + s];
    __syncthreads();
  }
  if (tid == 0) crossPart[blockIdx.x * JCHUNKS + blockIdx.y] = credA[0];
}

// ---------------------------------------------------------------------------
// Kernel 3: finalize — deterministic single-block reduction to the scalar.
// ---------------------------------------------------------------------------
__global__ __launch_bounds__(256) void finalize_kernel(
    const float* __restrict__ rowPart, const float* __restrict__ crossPart,
    float* __restrict__ out) {
  __shared__ float sA[256];
  __shared__ float sB[256];
  const int tid = threadIdx.x;

  float logAcc = 0.f;
  for (int i = tid; i < NROW; i += 256) {
    float s = 0.f;
#pragma unroll
    for (int c = 0; c < JCHUNKS; ++c) s += rowPart[(size_t)i * JCHUNKS + c];
    logAcc += logf(s - EXP10);
  }
  float crAcc = 0.f;
  for (int b = tid; b < (NROW / 64) * JCHUNKS; b += 256) crAcc += crossPart[b];

  sA[tid] = logAcc;
  sB[tid] = crAcc;
  __syncthreads();
  for (int s = 128; s > 0; s >>= 1) {
    if (tid < s) { sA[tid] += sA[tid + s]; sB[tid] += sB[tid + s]; }
    __syncthreads();
  }
  if (tid == 0) out[0] = (sA[0] - 2.0f * TINV * sB[0]) / (float)NROW;
}

// ---------------------------------------------------------------------------
extern "C" void kernel_launch(void* const* d_in, const int* in_sizes, int n_in,
                              void* d_out, int out_size, void* d_ws, size_t ws_size,
                              hipStream_t stream) {
  const float* emb0 = (const float*)d_in[0];
  const float* emb1 = (const float*)d_in[1];
  const float* loc0 = (const float*)d_in[2];
  const float* loc1 = (const float*)d_in[3];
  float* out = (float*)d_out;

  float* G         = (float*)d_ws;                 // 8192*64 f32 = 2 MB
  float* rowPart   = G + (size_t)NROW * CDIM;      // 8192*8 f32  = 256 KB
  float* crossPart = rowPart + (size_t)NROW * JCHUNKS;  // 1024 f32

  gather_kernel<<<(NROW * CDIM) / 256, 256, 0, stream>>>(emb0, emb1, loc0, loc1, G);

  dim3 grid(NROW / 64, JCHUNKS);
  simsum_kernel<<<grid, 256, 0, stream>>>(G, rowPart, crossPart);

  finalize_kernel<<<1, 256, 0, stream>>>(rowPart, crossPart, out);
}

// Round 3
// 115.809 us; speedup vs baseline: 1.2438x; 1.2438x over previous
//
#include <hip/hip_runtime.h>
#include <math.h>

// Problem constants (B=1, C=64, H=W=256, N=4096, T=0.1)
#define HW2     65536
#define NLOC    4096
#define NROW    8192
#define CDIM    64
#define TINV    10.0f
#define EXP10   22026.465794806718f   // exp(1/T)

// Fold 1/T (and exp->exp2 conversion if available) into the A-operand scale.
#if __has_builtin(__builtin_amdgcn_exp2f)
#define ASCALE  14.426950408889634f   // 10 * log2(e)
#define EXPFN(x) __builtin_amdgcn_exp2f(x)
#else
#define ASCALE  10.0f
#define EXPFN(x) __expf(x)
#endif

typedef __attribute__((ext_vector_type(8))) short bf16x8;
typedef __attribute__((ext_vector_type(4))) float f32x4;

__device__ __forceinline__ unsigned short f2bf(float f) {
  unsigned u = __builtin_bit_cast(unsigned, f);
  u += 0x7FFFu + ((u >> 16) & 1u);   // RNE
  return (unsigned short)(u >> 16);
}
__device__ __forceinline__ float bf2f(unsigned u16) {
  unsigned u = u16 << 16;
  return __builtin_bit_cast(float, u);
}

// ---------------------------------------------------------------------------
// Kernel 1: gather + bf16 convert.  Ga = bf16(G * ASCALE), Gb = bf16(G).
// ---------------------------------------------------------------------------
__global__ __launch_bounds__(256) void gather_kernel(
    const float* __restrict__ emb0, const float* __restrict__ emb1,
    const float* __restrict__ loc0, const float* __restrict__ loc1,
    unsigned short* __restrict__ Ga, unsigned short* __restrict__ Gb) {
  int t = blockIdx.x * 256 + threadIdx.x;   // 0 .. NROW*CDIM
  int i = t >> 6;
  int c = t & 63;
  const float* loc = (i < NLOC) ? loc0 : loc1;
  const float* emb = (i < NLOC) ? emb0 : emb1;
  int u = (i < NLOC) ? i : (i - NLOC);
  int ind = (int)floorf(loc[u * 2]) * 256 + (int)floorf(loc[u * 2 + 1]);
  float v = emb[(size_t)c * HW2 + ind];
  Gb[t] = f2bf(v);
  Ga[t] = f2bf(v * ASCALE);
}

// ---------------------------------------------------------------------------
// Kernel 2: MFMA Gram + fused exp-rowsum.
// Grid (128, 8): block = 64-row i-panel x 1024-col j-chunk, 4 waves.
// Wave w owns rows i0+w*16 .. +16; A-frags live in registers whole kernel.
// B-frags load straight from row-major G (L1/L2 resident, no LDS).
// NOTE: bf16x8 = 8 shorts = 16 B, so the k=[32,64) slice is index [4]!
// C/D layout: col = lane&15, row = (lane>>4)*4 + reg   [guide m89/m91]
// ---------------------------------------------------------------------------
__global__ __launch_bounds__(256) void simsum_kernel(
    const unsigned short* __restrict__ Ga,
    const unsigned short* __restrict__ Gb,
    float* __restrict__ rowPart) {
  const int tid   = threadIdx.x;
  const int lane  = tid & 63;
  const int wave  = tid >> 6;
  const int lrow  = lane & 15;    // A-row / B-col within fragment
  const int khalf = lane >> 4;    // k-group 0..3
  const int i0    = blockIdx.x * 64 + wave * 16;
  const int j0    = blockIdx.y * 1024;
  const int bj    = blockIdx.y;

  // A fragments (scaled), fixed for the whole kernel: rows i0+lrow.
  const bf16x8* arow =
      reinterpret_cast<const bf16x8*>(Ga + (size_t)(i0 + lrow) * CDIM + khalf * 8);
  bf16x8 a0 = arow[0];      // k in [0,32):  shorts [khalf*8,    +8)
  bf16x8 a1 = arow[4];      // k in [32,64): shorts [32+khalf*8, +8)

  float accExp[4][4];       // [nf][r] — separate chains per n-fragment
#pragma unroll
  for (int nf = 0; nf < 4; ++nf)
#pragma unroll
    for (int r = 0; r < 4; ++r) accExp[nf][r] = 0.f;

#pragma unroll 2
  for (int js = 0; js < 16; ++js) {
    const int jb = j0 + js * 64;
    bf16x8 b0[4], b1[4];
#pragma unroll
    for (int nf = 0; nf < 4; ++nf) {
      const bf16x8* brow = reinterpret_cast<const bf16x8*>(
          Gb + (size_t)(jb + nf * 16 + lrow) * CDIM + khalf * 8);
      b0[nf] = brow[0];
      b1[nf] = brow[4];
    }
    f32x4 acc[4];
#pragma unroll
    for (int nf = 0; nf < 4; ++nf) {
      f32x4 z = {0.f, 0.f, 0.f, 0.f};
      acc[nf] = __builtin_amdgcn_mfma_f32_16x16x32_bf16(a0, b0[nf], z, 0, 0, 0);
    }
#pragma unroll
    for (int nf = 0; nf < 4; ++nf)
      acc[nf] = __builtin_amdgcn_mfma_f32_16x16x32_bf16(a1, b1[nf], acc[nf], 0, 0, 0);
#pragma unroll
    for (int nf = 0; nf < 4; ++nf)
#pragma unroll
      for (int r = 0; r < 4; ++r) accExp[nf][r] += EXPFN(acc[nf][r]);
  }

  // Sum the 4 n-chains, then reduce across the 16 lanes holding one row.
#pragma unroll
  for (int r = 0; r < 4; ++r) {
    float v = (accExp[0][r] + accExp[1][r]) + (accExp[2][r] + accExp[3][r]);
    v += __shfl_xor(v, 1, 16);
    v += __shfl_xor(v, 2, 16);
    v += __shfl_xor(v, 4, 16);
    v += __shfl_xor(v, 8, 16);
    if (lrow == 0)
      rowPart[(size_t)(i0 + khalf * 4 + r) * 8 + bj] = v;
  }
}

// ---------------------------------------------------------------------------
// Kernel 3: finalize — log-sum over rows + f32 band dot from Gb + reduce.
// loss = [ sum_i log(rowsum_i - e^10) - (2/T) * sum_u sim[u][u+N] ] / (2N)
// ---------------------------------------------------------------------------
__global__ __launch_bounds__(256) void finalize_kernel(
    const unsigned short* __restrict__ Gb,
    const float* __restrict__ rowPart, float* __restrict__ out) {
  __shared__ float sA[256];
  __shared__ float sB[256];
  const int tid = threadIdx.x;

  float logAcc = 0.f;
  for (int i = tid; i < NROW; i += 256) {
    float s = 0.f;
#pragma unroll
    for (int c = 0; c < 8; ++c) s += rowPart[(size_t)i * 8 + c];
    logAcc += logf(s - EXP10);
  }

  float cross = 0.f;
  for (int u = tid; u < NLOC; u += 256) {
    const unsigned* r0 = reinterpret_cast<const unsigned*>(Gb + (size_t)u * CDIM);
    const unsigned* r1 =
        reinterpret_cast<const unsigned*>(Gb + (size_t)(u + NLOC) * CDIM);
    float d = 0.f;
#pragma unroll
    for (int c = 0; c < 32; ++c) {
      unsigned a = r0[c], b = r1[c];
      d += bf2f(a & 0xffffu) * bf2f(b & 0xffffu) + bf2f(a >> 16) * bf2f(b >> 16);
    }
    cross += d;
  }

  sA[tid] = logAcc;
  sB[tid] = cross;
  __syncthreads();
  for (int s = 128; s > 0; s >>= 1) {
    if (tid < s) { sA[tid] += sA[tid + s]; sB[tid] += sB[tid + s]; }
    __syncthreads();
  }
  if (tid == 0) out[0] = (sA[0] - 2.0f * TINV * sB[0]) / (float)NROW;
}

// ---------------------------------------------------------------------------
extern "C" void kernel_launch(void* const* d_in, const int* in_sizes, int n_in,
                              void* d_out, int out_size, void* d_ws, size_t ws_size,
                              hipStream_t stream) {
  const float* emb0 = (const float*)d_in[0];
  const float* emb1 = (const float*)d_in[1];
  const float* loc0 = (const float*)d_in[2];
  const float* loc1 = (const float*)d_in[3];
  float* out = (float*)d_out;

  unsigned short* Ga = (unsigned short*)d_ws;                 // 1 MB
  unsigned short* Gb = Ga + (size_t)NROW * CDIM;              // 1 MB
  float* rowPart = (float*)(Gb + (size_t)NROW * CDIM);        // 256 KB

  gather_kernel<<<(NROW * CDIM) / 256, 256, 0, stream>>>(emb0, emb1, loc0, loc1,
                                                         Ga, Gb);
  dim3 grid(NROW / 64, 8);
  simsum_kernel<<<grid, 256, 0, stream>>>(Ga, Gb, rowPart);
  finalize_kernel<<<1, 256, 0, stream>>>(Gb, rowPart, out);
}

// Round 4
// 53.441 us; speedup vs baseline: 2.6953x; 2.1670x over previous
//
#include <hip/hip_runtime.h>
#include <math.h>

// Problem constants (B=1, C=64, H=W=256, N=4096, T=0.1)
#define HW2     65536
#define NLOC    4096
#define NROW    8192
#define CDIM    64
#define TINV    10.0f
#define EXP10   22026.465794806718f   // exp(1/T)

#if __has_builtin(__builtin_amdgcn_exp2f)
#define ASCALE  14.426950408889634f   // 10 * log2(e)
#define EXPFN(x) __builtin_amdgcn_exp2f(x)
#else
#define ASCALE  10.0f
#define EXPFN(x) __expf(x)
#endif

typedef __attribute__((ext_vector_type(8))) short bf16x8;
typedef __attribute__((ext_vector_type(4))) float f32x4;
typedef unsigned short u16;

__device__ __forceinline__ unsigned short f2bf(float f) {
  unsigned u = __builtin_bit_cast(unsigned, f);
  u += 0x7FFFu + ((u >> 16) & 1u);   // RNE
  return (unsigned short)(u >> 16);
}
__device__ __forceinline__ float bf2f(unsigned u16v) {
  unsigned u = u16v << 16;
  return __builtin_bit_cast(float, u);
}

// ---------------------------------------------------------------------------
// Kernel T: transpose emb [64][65536] f32 -> embT [65536][64] bf16 (streamed).
// Block = 64ch x 64w tile; LDS tile padded to 72 shorts/row (16B-aligned).
// ---------------------------------------------------------------------------
__global__ __launch_bounds__(256) void transpose_kernel(
    const float* __restrict__ emb0, const float* __restrict__ emb1,
    u16* __restrict__ embT0, u16* __restrict__ embT1) {
  __shared__ u16 T[64 * 72];
  const int tid = threadIdx.x;
  const float* emb = blockIdx.y ? emb1 : emb0;
  u16* embT        = blockIdx.y ? embT1 : embT0;
  const int w0 = blockIdx.x * 64;

#pragma unroll
  for (int q = 0; q < 4; ++q) {
    const int c = q * 16 + (tid >> 4);
    const int x = tid & 15;
    float4 v = *reinterpret_cast<const float4*>(&emb[(size_t)c * HW2 + w0 + x * 4]);
    T[(x * 4 + 0) * 72 + c] = f2bf(v.x);
    T[(x * 4 + 1) * 72 + c] = f2bf(v.y);
    T[(x * 4 + 2) * 72 + c] = f2bf(v.z);
    T[(x * 4 + 3) * 72 + c] = f2bf(v.w);
  }
  __syncthreads();
#pragma unroll
  for (int q = 0; q < 2; ++q) {
    const int w  = q * 32 + (tid >> 3);
    const int c8 = tid & 7;
    bf16x8 v = *reinterpret_cast<const bf16x8*>(&T[w * 72 + c8 * 8]);
    *reinterpret_cast<bf16x8*>(&embT[(size_t)(w0 + w) * CDIM + c8 * 8]) = v;
  }
}

// ---------------------------------------------------------------------------
// Kernel G2: gather from transposed embT — 8 threads per output row, each
// reads one contiguous 16B piece of the 128B row.  Ga = bf16*ASCALE, Gb raw.
// ---------------------------------------------------------------------------
__global__ __launch_bounds__(256) void gather2_kernel(
    const u16* __restrict__ embT0, const u16* __restrict__ embT1,
    const float* __restrict__ loc0, const float* __restrict__ loc1,
    u16* __restrict__ Ga, u16* __restrict__ Gb) {
  const int t = blockIdx.x * 256 + threadIdx.x;   // 0 .. 65535
  const int i = t >> 3;
  const int p = t & 7;
  const float* loc = (i < NLOC) ? loc0 : loc1;
  const u16*   eT  = (i < NLOC) ? embT0 : embT1;
  const int u = (i < NLOC) ? i : i - NLOC;
  const int ind = (int)floorf(loc[u * 2]) * 256 + (int)floorf(loc[u * 2 + 1]);
  bf16x8 v = *reinterpret_cast<const bf16x8*>(&eT[(size_t)ind * CDIM + p * 8]);
  *reinterpret_cast<bf16x8*>(&Gb[(size_t)i * CDIM + p * 8]) = v;
  bf16x8 vs;
#pragma unroll
  for (int e = 0; e < 8; ++e) {
    float f = bf2f((unsigned short)v[e]);
    vs[e] = (short)f2bf(f * ASCALE);
  }
  *reinterpret_cast<bf16x8*>(&Ga[(size_t)i * CDIM + p * 8]) = vs;
}

// ---------------------------------------------------------------------------
// Kernel G (fallback if ws too small): direct scattered gather.
// ---------------------------------------------------------------------------
__global__ __launch_bounds__(256) void gather_kernel(
    const float* __restrict__ emb0, const float* __restrict__ emb1,
    const float* __restrict__ loc0, const float* __restrict__ loc1,
    u16* __restrict__ Ga, u16* __restrict__ Gb) {
  int t = blockIdx.x * 256 + threadIdx.x;
  int i = t >> 6;
  int c = t & 63;
  const float* loc = (i < NLOC) ? loc0 : loc1;
  const float* emb = (i < NLOC) ? emb0 : emb1;
  int u = (i < NLOC) ? i : (i - NLOC);
  int ind = (int)floorf(loc[u * 2]) * 256 + (int)floorf(loc[u * 2 + 1]);
  float v = emb[(size_t)c * HW2 + ind];
  Gb[t] = f2bf(v);
  Ga[t] = f2bf(v * ASCALE);
}

// ---------------------------------------------------------------------------
// Kernel S: MFMA Gram + fused exp-rowsum, LDS-staged shared B (2-phase dbuf).
//
// LDS tile (per buffer): 64 rows x 128B, XOR seg-swizzle:
//   phys(row, seg) holds logical seg^(row&7)  (seg = 16B unit, 8 per row)
// Staged via global_load_lds (linear dest = base + lane*16) with the inverse
// swizzle applied to the per-lane GLOBAL source address (rule #21).
// ds_read frag addr: row R, logical seg sl -> phys byte R*128 + (sl^(R&7))*16.
// ---------------------------------------------------------------------------
__device__ __forceinline__ void stage_tile(u16* Bs, const u16* __restrict__ Gb,
                                           int jb, int buf, int tid, int wave,
                                           int srow, int ssl) {
#pragma unroll
  for (int r = 0; r < 2; ++r) {
    const u16* src = Gb + (size_t)(jb + r * 32 + srow) * CDIM + ssl * 8;
#if __has_builtin(__builtin_amdgcn_global_load_lds)
    // wave-uniform LDS base (shorts): buf*4096 + r*2048 + wave*512; HW adds lane*16B
    u16* dst = Bs + buf * 4096 + r * 2048 + wave * 512;
    __builtin_amdgcn_global_load_lds(
        (const __attribute__((address_space(1))) unsigned int*)src,
        (__attribute__((address_space(3))) unsigned int*)dst, 16, 0, 0);
#else
    bf16x8 tmp = *reinterpret_cast<const bf16x8*>(src);
    *reinterpret_cast<bf16x8*>(Bs + buf * 4096 + r * 2048 + tid * 8) = tmp;
#endif
  }
}

__global__ __launch_bounds__(256) void simsum_kernel(
    const u16* __restrict__ Ga, const u16* __restrict__ Gb,
    float* __restrict__ rowPart) {
  __shared__ u16 Bs[2 * 64 * CDIM];   // 2 x 8KB
  const int tid  = threadIdx.x;
  const int lane = tid & 63;
  const int wave = tid >> 6;
  const int lrow = lane & 15;
  const int kh   = lane >> 4;
  const int i0 = blockIdx.x * 64 + wave * 16;
  const int j0 = blockIdx.y * 1024;

  // A fragments (scaled), registers for whole kernel. bf16x8* steps 8 shorts!
  const bf16x8* arow =
      reinterpret_cast<const bf16x8*>(Ga + (size_t)(i0 + lrow) * CDIM + kh * 8);
  bf16x8 a0 = arow[0];   // k [0,32)
  bf16x8 a1 = arow[4];   // k [32,64)

  // staging thread constants
  const int srow = tid >> 3;                // row 0..31 (round adds 32)
  const int ssl  = (tid & 7) ^ (srow & 7);  // logical seg this thread fetches

  // frag-read phys seg offsets (shorts)
  const int sp0 = ((kh ^ (lrow & 7)) << 3);
  const int sp1 = (((4 + kh) ^ (lrow & 7)) << 3);

  float accExp[4][4];
#pragma unroll
  for (int nf = 0; nf < 4; ++nf)
#pragma unroll
    for (int r = 0; r < 4; ++r) accExp[nf][r] = 0.f;

  stage_tile(Bs, Gb, j0, 0, tid, wave, srow, ssl);
  __syncthreads();

  int cur = 0;
  for (int js = 0; js < 16; ++js) {
    if (js < 15) stage_tile(Bs, Gb, j0 + (js + 1) * 64, cur ^ 1, tid, wave, srow, ssl);

    const u16* bs = Bs + cur * 4096;
    f32x4 acc[4];
#pragma unroll
    for (int nf = 0; nf < 4; ++nf) {
      const int rb = (nf * 16 + lrow) * CDIM;
      bf16x8 b0 = *reinterpret_cast<const bf16x8*>(bs + rb + sp0);
      bf16x8 b1 = *reinterpret_cast<const bf16x8*>(bs + rb + sp1);
      f32x4 z = {0.f, 0.f, 0.f, 0.f};
      acc[nf] = __builtin_amdgcn_mfma_f32_16x16x32_bf16(a0, b0, z, 0, 0, 0);
      acc[nf] = __builtin_amdgcn_mfma_f32_16x16x32_bf16(a1, b1, acc[nf], 0, 0, 0);
    }
#pragma unroll
    for (int nf = 0; nf < 4; ++nf)
#pragma unroll
      for (int r = 0; r < 4; ++r) accExp[nf][r] += EXPFN(acc[nf][r]);

    __syncthreads();   // drains vmcnt (stage done) + lgkmcnt; swap buffers
    cur ^= 1;
  }

  // Sum 4 n-chains, reduce across the 16 lanes holding one row.
#pragma unroll
  for (int r = 0; r < 4; ++r) {
    float v = (accExp[0][r] + accExp[1][r]) + (accExp[2][r] + accExp[3][r]);
    v += __shfl_xor(v, 1, 16);
    v += __shfl_xor(v, 2, 16);
    v += __shfl_xor(v, 4, 16);
    v += __shfl_xor(v, 8, 16);
    if (lrow == 0)
      rowPart[(size_t)(i0 + kh * 4 + r) * 8 + blockIdx.y] = v;
  }
}

// ---------------------------------------------------------------------------
// Kernel F1: per-block partials — log(rowsum - e^10) over 128 rows + band dot
// over 64 u's.  Kernel F2: one wave reduces the 64 partials.
// ---------------------------------------------------------------------------
__global__ __launch_bounds__(256) void finpart_kernel(
    const u16* __restrict__ Gb, const float* __restrict__ rowPart,
    float* __restrict__ partA, float* __restrict__ partB) {
  __shared__ float sA[256];
  __shared__ float sB[256];
  const int tid = threadIdx.x, b = blockIdx.x;

  float logAcc = 0.f;
  if (tid < 128) {
    const int row = b * 128 + tid;
    float s = 0.f;
#pragma unroll
    for (int c = 0; c < 8; ++c) s += rowPart[(size_t)row * 8 + c];
    logAcc = logf(s - EXP10);
  }
  float cross = 0.f;
  if (tid < 64) {
    const int u = b * 64 + tid;
    const unsigned* r0 = reinterpret_cast<const unsigned*>(Gb + (size_t)u * CDIM);
    const unsigned* r1 =
        reinterpret_cast<const unsigned*>(Gb + (size_t)(u + NLOC) * CDIM);
#pragma unroll
    for (int c = 0; c < 32; ++c) {
      unsigned a = r0[c], bb = r1[c];
      cross += bf2f(a & 0xffffu) * bf2f(bb & 0xffffu) + bf2f(a >> 16) * bf2f(bb >> 16);
    }
  }
  sA[tid] = logAcc;
  sB[tid] = cross;
  __syncthreads();
  for (int s = 128; s > 0; s >>= 1) {
    if (tid < s) { sA[tid] += sA[tid + s]; sB[tid] += sB[tid + s]; }
    __syncthreads();
  }
  if (tid == 0) { partA[b] = sA[0]; partB[b] = sB[0]; }
}

__global__ __launch_bounds__(64) void fin2_kernel(
    const float* __restrict__ partA, const float* __restrict__ partB,
    float* __restrict__ out) {
  const int l = threadIdx.x;
  float a = partA[l];
  float c = partB[l];
#pragma unroll
  for (int s = 1; s < 64; s <<= 1) {
    a += __shfl_xor(a, s, 64);
    c += __shfl_xor(c, s, 64);
  }
  if (l == 0) out[0] = (a - 2.0f * TINV * c) / (float)NROW;
}

// ---------------------------------------------------------------------------
extern "C" void kernel_launch(void* const* d_in, const int* in_sizes, int n_in,
                              void* d_out, int out_size, void* d_ws, size_t ws_size,
                              hipStream_t stream) {
  const float* emb0 = (const float*)d_in[0];
  const float* emb1 = (const float*)d_in[1];
  const float* loc0 = (const float*)d_in[2];
  const float* loc1 = (const float*)d_in[3];
  float* out = (float*)d_out;
  char* ws = (char*)d_ws;

  const size_t NEED = (18ull << 20) + (256ull << 10) + (8ull << 10);
  u16 *Ga, *Gb;
  float *rowPart, *partA, *partB;

  if (ws_size >= NEED) {
    u16* embT0 = (u16*)(ws);
    u16* embT1 = (u16*)(ws + (8ull << 20));
    Ga = (u16*)(ws + (16ull << 20));
    Gb = (u16*)(ws + (17ull << 20));
    rowPart = (float*)(ws + (18ull << 20));
    partA = (float*)(ws + (18ull << 20) + (256ull << 10));
    partB = partA + 64;

    dim3 tg(HW2 / 64, 2);
    transpose_kernel<<<tg, 256, 0, stream>>>(emb0, emb1, embT0, embT1);
    gather2_kernel<<<(NROW * 8) / 256, 256, 0, stream>>>(embT0, embT1, loc0, loc1,
                                                         Ga, Gb);
  } else {
    Ga = (u16*)ws;
    Gb = Ga + (size_t)NROW * CDIM;
    rowPart = (float*)(Gb + (size_t)NROW * CDIM);
    partA = rowPart + (size_t)NROW * 8;
    partB = partA + 64;
    gather_kernel<<<(NROW * CDIM) / 256, 256, 0, stream>>>(emb0, emb1, loc0, loc1,
                                                           Ga, Gb);
  }

  dim3 grid(NROW / 64, 8);
  simsum_kernel<<<grid, 256, 0, stream>>>(Ga, Gb, rowPart);
  finpart_kernel<<<64, 256, 0, stream>>>(Gb, rowPart, partA, partB);
  fin2_kernel<<<1, 64, 0, stream>>>(partA, partB, out);
}

// Round 5
// 45.531 us; speedup vs baseline: 3.1636x; 1.1737x over previous
//
#include <hip/hip_runtime.h>
#include <math.h>

// Problem constants (B=1, C=64, H=W=256, N=4096, T=0.1)
#define HW2     65536
#define NLOC    4096
#define NROW    8192
#define CDIM    64
#define TINV    10.0f
#define EXP10   22026.465794806718f   // exp(1/T)
#define JCHUNKS 16
#define JCHUNK  512        // NROW / JCHUNKS

#if __has_builtin(__builtin_amdgcn_exp2f)
#define ASCALE  14.426950408889634f   // 10 * log2(e)
#define EXPFN(x) __builtin_amdgcn_exp2f(x)
#else
#define ASCALE  10.0f
#define EXPFN(x) __expf(x)
#endif

typedef __attribute__((ext_vector_type(8))) short bf16x8;
typedef __attribute__((ext_vector_type(4))) float f32x4;
typedef unsigned short u16;

__device__ __forceinline__ unsigned short f2bf(float f) {
  unsigned u = __builtin_bit_cast(unsigned, f);
  u += 0x7FFFu + ((u >> 16) & 1u);   // RNE
  return (unsigned short)(u >> 16);
}
__device__ __forceinline__ float bf2f(unsigned u16v) {
  unsigned u = u16v << 16;
  return __builtin_bit_cast(float, u);
}

// ---------------------------------------------------------------------------
// Kernel T: transpose emb [64][65536] f32 -> embT [65536][64] bf16 (streamed).
// ---------------------------------------------------------------------------
__global__ __launch_bounds__(256) void transpose_kernel(
    const float* __restrict__ emb0, const float* __restrict__ emb1,
    u16* __restrict__ embT0, u16* __restrict__ embT1) {
  __shared__ u16 T[64 * 72];
  const int tid = threadIdx.x;
  const float* emb = blockIdx.y ? emb1 : emb0;
  u16* embT        = blockIdx.y ? embT1 : embT0;
  const int w0 = blockIdx.x * 64;

#pragma unroll
  for (int q = 0; q < 4; ++q) {
    const int c = q * 16 + (tid >> 4);
    const int x = tid & 15;
    float4 v = *reinterpret_cast<const float4*>(&emb[(size_t)c * HW2 + w0 + x * 4]);
    T[(x * 4 + 0) * 72 + c] = f2bf(v.x);
    T[(x * 4 + 1) * 72 + c] = f2bf(v.y);
    T[(x * 4 + 2) * 72 + c] = f2bf(v.z);
    T[(x * 4 + 3) * 72 + c] = f2bf(v.w);
  }
  __syncthreads();
#pragma unroll
  for (int q = 0; q < 2; ++q) {
    const int w  = q * 32 + (tid >> 3);
    const int c8 = tid & 7;
    bf16x8 v = *reinterpret_cast<const bf16x8*>(&T[w * 72 + c8 * 8]);
    *reinterpret_cast<bf16x8*>(&embT[(size_t)(w0 + w) * CDIM + c8 * 8]) = v;
  }
}

// ---------------------------------------------------------------------------
// Kernel G2: gather rows from transposed embT (contiguous 128B rows).
// ---------------------------------------------------------------------------
__global__ __launch_bounds__(256) void gather2_kernel(
    const u16* __restrict__ embT0, const u16* __restrict__ embT1,
    const float* __restrict__ loc0, const float* __restrict__ loc1,
    u16* __restrict__ Ga, u16* __restrict__ Gb) {
  const int t = blockIdx.x * 256 + threadIdx.x;   // 0 .. 65535
  const int i = t >> 3;
  const int p = t & 7;
  const float* loc = (i < NLOC) ? loc0 : loc1;
  const u16*   eT  = (i < NLOC) ? embT0 : embT1;
  const int u = (i < NLOC) ? i : i - NLOC;
  const int ind = (int)floorf(loc[u * 2]) * 256 + (int)floorf(loc[u * 2 + 1]);
  bf16x8 v = *reinterpret_cast<const bf16x8*>(&eT[(size_t)ind * CDIM + p * 8]);
  *reinterpret_cast<bf16x8*>(&Gb[(size_t)i * CDIM + p * 8]) = v;
  bf16x8 vs;
#pragma unroll
  for (int e = 0; e < 8; ++e) {
    float f = bf2f((unsigned short)v[e]);
    vs[e] = (short)f2bf(f * ASCALE);
  }
  *reinterpret_cast<bf16x8*>(&Ga[(size_t)i * CDIM + p * 8]) = vs;
}

// ---------------------------------------------------------------------------
// Kernel G (fallback if ws too small): direct scattered gather.
// ---------------------------------------------------------------------------
__global__ __launch_bounds__(256) void gather_kernel(
    const float* __restrict__ emb0, const float* __restrict__ emb1,
    const float* __restrict__ loc0, const float* __restrict__ loc1,
    u16* __restrict__ Ga, u16* __restrict__ Gb) {
  int t = blockIdx.x * 256 + threadIdx.x;
  int i = t >> 6;
  int c = t & 63;
  const float* loc = (i < NLOC) ? loc0 : loc1;
  const float* emb = (i < NLOC) ? emb0 : emb1;
  int u = (i < NLOC) ? i : (i - NLOC);
  int ind = (int)floorf(loc[u * 2]) * 256 + (int)floorf(loc[u * 2 + 1]);
  float v = emb[(size_t)c * HW2 + ind];
  Gb[t] = f2bf(v);
  Ga[t] = f2bf(v * ASCALE);
}

// ---------------------------------------------------------------------------
// Kernel S: MFMA Gram + fused exp-rowsum.  128-row i-panels, 512-col chunks.
// LDS B-tile per step: 64 rows x 128B, XOR seg-swizzle (identical to R4,
// SQ_LDS_BANK_CONFLICT measured 0).  Staging halved: grid.x=64 -> 67MB L2.
// ---------------------------------------------------------------------------
__device__ __forceinline__ void stage_tile(u16* Bs, const u16* __restrict__ Gb,
                                           int jb, int buf, int tid, int wave,
                                           int srow, int ssl) {
#pragma unroll
  for (int r = 0; r < 2; ++r) {
    const u16* src = Gb + (size_t)(jb + r * 32 + srow) * CDIM + ssl * 8;
#if __has_builtin(__builtin_amdgcn_global_load_lds)
    u16* dst = Bs + buf * 4096 + r * 2048 + wave * 512;
    __builtin_amdgcn_global_load_lds(
        (const __attribute__((address_space(1))) unsigned int*)src,
        (__attribute__((address_space(3))) unsigned int*)dst, 16, 0, 0);
#else
    bf16x8 tmp = *reinterpret_cast<const bf16x8*>(src);
    *reinterpret_cast<bf16x8*>(Bs + buf * 4096 + r * 2048 + tid * 8) = tmp;
#endif
  }
}

__global__ __launch_bounds__(256) void simsum_kernel(
    const u16* __restrict__ Ga, const u16* __restrict__ Gb,
    float* __restrict__ rowPart) {
  __shared__ u16 Bs[2 * 64 * CDIM];   // 2 x 8KB
  const int tid  = threadIdx.x;
  const int lane = tid & 63;
  const int wave = tid >> 6;
  const int lrow = lane & 15;
  const int kh   = lane >> 4;
  const int i0 = blockIdx.x * 128 + wave * 32;   // wave owns 32 rows
  const int j0 = blockIdx.y * JCHUNK;

  // Two 16-row A-panels per wave, registers for whole kernel.
  const bf16x8* arowA =
      reinterpret_cast<const bf16x8*>(Ga + (size_t)(i0 + lrow) * CDIM + kh * 8);
  const bf16x8* arowB =
      reinterpret_cast<const bf16x8*>(Ga + (size_t)(i0 + 16 + lrow) * CDIM + kh * 8);
  bf16x8 aA0 = arowA[0], aA1 = arowA[4];   // k [0,32), [32,64)
  bf16x8 aB0 = arowB[0], aB1 = arowB[4];

  const int srow = tid >> 3;
  const int ssl  = (tid & 7) ^ (srow & 7);
  const int sp0 = ((kh ^ (lrow & 7)) << 3);
  const int sp1 = (((4 + kh) ^ (lrow & 7)) << 3);

  float accA[4][4], accB[4][4];
#pragma unroll
  for (int nf = 0; nf < 4; ++nf)
#pragma unroll
    for (int r = 0; r < 4; ++r) { accA[nf][r] = 0.f; accB[nf][r] = 0.f; }

  stage_tile(Bs, Gb, j0, 0, tid, wave, srow, ssl);
  __syncthreads();

  int cur = 0;
  for (int js = 0; js < JCHUNK / 64; ++js) {
    if (js < JCHUNK / 64 - 1)
      stage_tile(Bs, Gb, j0 + (js + 1) * 64, cur ^ 1, tid, wave, srow, ssl);

    const u16* bs = Bs + cur * 4096;
#pragma unroll
    for (int nf = 0; nf < 4; ++nf) {
      const int rb = (nf * 16 + lrow) * CDIM;
      bf16x8 b0 = *reinterpret_cast<const bf16x8*>(bs + rb + sp0);
      bf16x8 b1 = *reinterpret_cast<const bf16x8*>(bs + rb + sp1);
      f32x4 z = {0.f, 0.f, 0.f, 0.f};
      f32x4 tA = __builtin_amdgcn_mfma_f32_16x16x32_bf16(aA0, b0, z, 0, 0, 0);
      tA = __builtin_amdgcn_mfma_f32_16x16x32_bf16(aA1, b1, tA, 0, 0, 0);
      f32x4 tB = __builtin_amdgcn_mfma_f32_16x16x32_bf16(aB0, b0, z, 0, 0, 0);
      tB = __builtin_amdgcn_mfma_f32_16x16x32_bf16(aB1, b1, tB, 0, 0, 0);
#pragma unroll
      for (int r = 0; r < 4; ++r) {
        accA[nf][r] += EXPFN(tA[r]);
        accB[nf][r] += EXPFN(tB[r]);
      }
    }

    __syncthreads();   // drains vmcnt (stage done) + lgkmcnt; swap buffers
    cur ^= 1;
  }

#pragma unroll
  for (int r = 0; r < 4; ++r) {
    float vA = (accA[0][r] + accA[1][r]) + (accA[2][r] + accA[3][r]);
    float vB = (accB[0][r] + accB[1][r]) + (accB[2][r] + accB[3][r]);
    vA += __shfl_xor(vA, 1, 16);
    vA += __shfl_xor(vA, 2, 16);
    vA += __shfl_xor(vA, 4, 16);
    vA += __shfl_xor(vA, 8, 16);
    vB += __shfl_xor(vB, 1, 16);
    vB += __shfl_xor(vB, 2, 16);
    vB += __shfl_xor(vB, 4, 16);
    vB += __shfl_xor(vB, 8, 16);
    if (lrow == 0) {
      rowPart[(size_t)(i0 + kh * 4 + r) * JCHUNKS + blockIdx.y] = vA;
      rowPart[(size_t)(i0 + 16 + kh * 4 + r) * JCHUNKS + blockIdx.y] = vB;
    }
  }
}

// ---------------------------------------------------------------------------
// Kernel F1: per-block partials; F2: one wave reduces the 64 partials.
// ---------------------------------------------------------------------------
__global__ __launch_bounds__(256) void finpart_kernel(
    const u16* __restrict__ Gb, const float* __restrict__ rowPart,
    float* __restrict__ partA, float* __restrict__ partB) {
  __shared__ float sA[256];
  __shared__ float sB[256];
  const int tid = threadIdx.x, b = blockIdx.x;

  float logAcc = 0.f;
  if (tid < 128) {
    const int row = b * 128 + tid;
    float s = 0.f;
#pragma unroll
    for (int c = 0; c < JCHUNKS; ++c) s += rowPart[(size_t)row * JCHUNKS + c];
    logAcc = logf(s - EXP10);
  }
  float cross = 0.f;
  if (tid < 64) {
    const int u = b * 64 + tid;
    const unsigned* r0 = reinterpret_cast<const unsigned*>(Gb + (size_t)u * CDIM);
    const unsigned* r1 =
        reinterpret_cast<const unsigned*>(Gb + (size_t)(u + NLOC) * CDIM);
#pragma unroll
    for (int c = 0; c < 32; ++c) {
      unsigned a = r0[c], bb = r1[c];
      cross += bf2f(a & 0xffffu) * bf2f(bb & 0xffffu) + bf2f(a >> 16) * bf2f(bb >> 16);
    }
  }
  sA[tid] = logAcc;
  sB[tid] = cross;
  __syncthreads();
  for (int s = 128; s > 0; s >>= 1) {
    if (tid < s) { sA[tid] += sA[tid + s]; sB[tid] += sB[tid + s]; }
    __syncthreads();
  }
  if (tid == 0) { partA[b] = sA[0]; partB[b] = sB[0]; }
}

__global__ __launch_bounds__(64) void fin2_kernel(
    const float* __restrict__ partA, const float* __restrict__ partB,
    float* __restrict__ out) {
  const int l = threadIdx.x;
  float a = partA[l];
  float c = partB[l];
#pragma unroll
  for (int s = 1; s < 64; s <<= 1) {
    a += __shfl_xor(a, s, 64);
    c += __shfl_xor(c, s, 64);
  }
  if (l == 0) out[0] = (a - 2.0f * TINV * c) / (float)NROW;
}

// ---------------------------------------------------------------------------
extern "C" void kernel_launch(void* const* d_in, const int* in_sizes, int n_in,
                              void* d_out, int out_size, void* d_ws, size_t ws_size,
                              hipStream_t stream) {
  const float* emb0 = (const float*)d_in[0];
  const float* emb1 = (const float*)d_in[1];
  const float* loc0 = (const float*)d_in[2];
  const float* loc1 = (const float*)d_in[3];
  float* out = (float*)d_out;
  char* ws = (char*)d_ws;

  const size_t NEED = (18ull << 20) + (512ull << 10) + (8ull << 10);
  u16 *Ga, *Gb;
  float *rowPart, *partA, *partB;

  if (ws_size >= NEED) {
    u16* embT0 = (u16*)(ws);
    u16* embT1 = (u16*)(ws + (8ull << 20));
    Ga = (u16*)(ws + (16ull << 20));
    Gb = (u16*)(ws + (17ull << 20));
    rowPart = (float*)(ws + (18ull << 20));
    partA = (float*)(ws + (18ull << 20) + (512ull << 10));
    partB = partA + 64;

    dim3 tg(HW2 / 64, 2);
    transpose_kernel<<<tg, 256, 0, stream>>>(emb0, emb1, embT0, embT1);
    gather2_kernel<<<(NROW * 8) / 256, 256, 0, stream>>>(embT0, embT1, loc0, loc1,
                                                         Ga, Gb);
  } else {
    Ga = (u16*)ws;
    Gb = Ga + (size_t)NROW * CDIM;
    rowPart = (float*)(Gb + (size_t)NROW * CDIM);
    partA = rowPart + (size_t)NROW * JCHUNKS;
    partB = partA + 64;
    gather_kernel<<<(NROW * CDIM) / 256, 256, 0, stream>>>(emb0, emb1, loc0, loc1,
                                                           Ga, Gb);
  }

  dim3 grid(NROW / 128, JCHUNKS);
  simsum_kernel<<<grid, 256, 0, stream>>>(Ga, Gb, rowPart);
  finpart_kernel<<<64, 256, 0, stream>>>(Gb, rowPart, partA, partB);
  fin2_kernel<<<1, 64, 0, stream>>>(partA, partB, out);
}

// Round 6
// 38.522 us; speedup vs baseline: 3.7392x; 1.1819x over previous
//
#include <hip/hip_runtime.h>
#include <math.h>

// Problem constants (B=1, C=64, H=W=256, N=4096, T=0.1)
#define HW2     65536
#define NLOC    4096
#define NROW    8192
#define CDIM    64
#define TINV    10.0f
#define EXP10   22026.465794806718f   // exp(1/T)
#define NP      64                    // 128-row panels
#define NPAIR   2080                  // NP*(NP+1)/2

#if __has_builtin(__builtin_amdgcn_exp2f)
#define ASCALE  14.426950408889634f   // 10 * log2(e)
#define EXPFN(x) __builtin_amdgcn_exp2f(x)
#else
#define ASCALE  10.0f
#define EXPFN(x) __expf(x)
#endif

typedef __attribute__((ext_vector_type(8))) short bf16x8;
typedef __attribute__((ext_vector_type(4))) float f32x4;
typedef unsigned short u16;

__device__ __forceinline__ unsigned short f2bf(float f) {
  unsigned u = __builtin_bit_cast(unsigned, f);
  u += 0x7FFFu + ((u >> 16) & 1u);   // RNE
  return (unsigned short)(u >> 16);
}
__device__ __forceinline__ float bf2f(unsigned u16v) {
  unsigned u = u16v << 16;
  return __builtin_bit_cast(float, u);
}

// ---------------------------------------------------------------------------
// Kernel T: transpose emb [64][65536] f32 -> embT [65536][64] bf16 (streamed).
// ---------------------------------------------------------------------------
__global__ __launch_bounds__(256) void transpose_kernel(
    const float* __restrict__ emb0, const float* __restrict__ emb1,
    u16* __restrict__ embT0, u16* __restrict__ embT1) {
  __shared__ u16 T[64 * 72];
  const int tid = threadIdx.x;
  const float* emb = blockIdx.y ? emb1 : emb0;
  u16* embT        = blockIdx.y ? embT1 : embT0;
  const int w0 = blockIdx.x * 64;

#pragma unroll
  for (int q = 0; q < 4; ++q) {
    const int c = q * 16 + (tid >> 4);
    const int x = tid & 15;
    float4 v = *reinterpret_cast<const float4*>(&emb[(size_t)c * HW2 + w0 + x * 4]);
    T[(x * 4 + 0) * 72 + c] = f2bf(v.x);
    T[(x * 4 + 1) * 72 + c] = f2bf(v.y);
    T[(x * 4 + 2) * 72 + c] = f2bf(v.z);
    T[(x * 4 + 3) * 72 + c] = f2bf(v.w);
  }
  __syncthreads();
#pragma unroll
  for (int q = 0; q < 2; ++q) {
    const int w  = q * 32 + (tid >> 3);
    const int c8 = tid & 7;
    bf16x8 v = *reinterpret_cast<const bf16x8*>(&T[w * 72 + c8 * 8]);
    *reinterpret_cast<bf16x8*>(&embT[(size_t)(w0 + w) * CDIM + c8 * 8]) = v;
  }
}

// ---------------------------------------------------------------------------
// Kernel G2: gather rows from transposed embT (contiguous 128B rows).
// ---------------------------------------------------------------------------
__global__ __launch_bounds__(256) void gather2_kernel(
    const u16* __restrict__ embT0, const u16* __restrict__ embT1,
    const float* __restrict__ loc0, const float* __restrict__ loc1,
    u16* __restrict__ Ga, u16* __restrict__ Gb) {
  const int t = blockIdx.x * 256 + threadIdx.x;   // 0 .. 65535
  const int i = t >> 3;
  const int p = t & 7;
  const float* loc = (i < NLOC) ? loc0 : loc1;
  const u16*   eT  = (i < NLOC) ? embT0 : embT1;
  const int u = (i < NLOC) ? i : i - NLOC;
  const int ind = (int)floorf(loc[u * 2]) * 256 + (int)floorf(loc[u * 2 + 1]);
  bf16x8 v = *reinterpret_cast<const bf16x8*>(&eT[(size_t)ind * CDIM + p * 8]);
  *reinterpret_cast<bf16x8*>(&Gb[(size_t)i * CDIM + p * 8]) = v;
  bf16x8 vs;
#pragma unroll
  for (int e = 0; e < 8; ++e) {
    float f = bf2f((unsigned short)v[e]);
    vs[e] = (short)f2bf(f * ASCALE);
  }
  *reinterpret_cast<bf16x8*>(&Ga[(size_t)i * CDIM + p * 8]) = vs;
}

// ---------------------------------------------------------------------------
// Kernel G (fallback if ws too small): direct scattered gather.
// ---------------------------------------------------------------------------
__global__ __launch_bounds__(256) void gather_kernel(
    const float* __restrict__ emb0, const float* __restrict__ emb1,
    const float* __restrict__ loc0, const float* __restrict__ loc1,
    u16* __restrict__ Ga, u16* __restrict__ Gb) {
  int t = blockIdx.x * 256 + threadIdx.x;
  int i = t >> 6;
  int c = t & 63;
  const float* loc = (i < NLOC) ? loc0 : loc1;
  const float* emb = (i < NLOC) ? emb0 : emb1;
  int u = (i < NLOC) ? i : (i - NLOC);
  int ind = (int)floorf(loc[u * 2]) * 256 + (int)floorf(loc[u * 2 + 1]);
  float v = emb[(size_t)c * HW2 + ind];
  Gb[t] = f2bf(v);
  Ga[t] = f2bf(v * ASCALE);
}

// ---------------------------------------------------------------------------
// Staging: one 64-row x 128B tile, XOR seg-swizzle (measured 0 conflicts).
//   phys(row, seg) holds logical seg^(row&7); linear LDS dest + inverse-
//   swizzled global source (rule #21).
// ---------------------------------------------------------------------------
__device__ __forceinline__ void stage_tile(u16* Bs, const u16* __restrict__ Gb,
                                           int jb, int buf, int tid, int wave,
                                           int srow, int ssl) {
#pragma unroll
  for (int r = 0; r < 2; ++r) {
    const u16* src = Gb + (size_t)(jb + r * 32 + srow) * CDIM + ssl * 8;
#if __has_builtin(__builtin_amdgcn_global_load_lds)
    u16* dst = Bs + buf * 4096 + r * 2048 + wave * 512;
    __builtin_amdgcn_global_load_lds(
        (const __attribute__((address_space(1))) unsigned int*)src,
        (__attribute__((address_space(3))) unsigned int*)dst, 16, 0, 0);
#else
    bf16x8 tmp = *reinterpret_cast<const bf16x8*>(src);
    *reinterpret_cast<bf16x8*>(Bs + buf * 4096 + r * 2048 + tid * 8) = tmp;
#endif
  }
}

// ---------------------------------------------------------------------------
// Kernel S (triangular): block b -> panel pair (p,q), p<=q, 128x128 tile.
// Row-sums of exp-tile -> rowPart[p-rows][q]; col-sums -> rowPart[q-rows][p]
// (skipped for p==q).  Each (row, slot) written exactly once; no atomics.
// ---------------------------------------------------------------------------
__global__ __launch_bounds__(256) void simsum_tri_kernel(
    const u16* __restrict__ Ga, const u16* __restrict__ Gb,
    float* __restrict__ rowPart) {
  __shared__ u16 Bs[2 * 64 * CDIM];    // 16 KB: q-panel as two swizzled tiles
  __shared__ float colRed[4][128];     // 2 KB cross-wave col-sum reduce

  const int tid  = threadIdx.x;
  const int lane = tid & 63;
  const int wave = tid >> 6;
  const int lrow = lane & 15;
  const int kh   = lane >> 4;

  // Triangular decode: b -> (p,q).  cnt(p) = p*NP - p(p-1)/2 pairs before p.
  const int b = blockIdx.x;
  int p = (int)((129.0f - sqrtf(16641.0f - 8.0f * (float)b)) * 0.5f);
  if (p < 0) p = 0;
  if (p > NP - 1) p = NP - 1;
#pragma unroll
  for (int it = 0; it < 3; ++it) {
    if (p > 0 && (p * NP - p * (p - 1) / 2) > b) --p;
    else if (((p + 1) * NP - (p + 1) * p / 2) <= b) ++p;
  }
  const int q  = p + (b - (p * NP - p * (p - 1) / 2));
  const int p0 = p * 128, q0 = q * 128;
  const int i0 = p0 + wave * 32;       // wave owns 32 p-rows

  // A fragments (scaled), registers whole kernel.  bf16x8* steps 8 shorts.
  const bf16x8* arowA =
      reinterpret_cast<const bf16x8*>(Ga + (size_t)(i0 + lrow) * CDIM + kh * 8);
  const bf16x8* arowB =
      reinterpret_cast<const bf16x8*>(Ga + (size_t)(i0 + 16 + lrow) * CDIM + kh * 8);
  bf16x8 aA0 = arowA[0], aA1 = arowA[4];   // k [0,32), [32,64)
  bf16x8 aB0 = arowB[0], aB1 = arowB[4];

  // Stage whole q-panel (128 rows) as two 64-row tiles, one barrier.
  const int srow = tid >> 3;
  const int ssl  = (tid & 7) ^ (srow & 7);
  stage_tile(Bs, Gb, q0,      0, tid, wave, srow, ssl);
  stage_tile(Bs, Gb, q0 + 64, 1, tid, wave, srow, ssl);
  __syncthreads();   // compiler drains vmcnt before s_barrier

  const int sp0 = ((kh ^ (lrow & 7)) << 3);
  const int sp1 = (((4 + kh) ^ (lrow & 7)) << 3);

  float accA[4][4], accB[4][4];
#pragma unroll
  for (int nf = 0; nf < 4; ++nf)
#pragma unroll
    for (int r = 0; r < 4; ++r) { accA[nf][r] = 0.f; accB[nf][r] = 0.f; }
  float colAcc[2][4];

#pragma unroll
  for (int t = 0; t < 2; ++t) {
    const u16* bs = Bs + t * 4096;
#pragma unroll
    for (int nf = 0; nf < 4; ++nf) {
      const int rb = (nf * 16 + lrow) * CDIM;
      bf16x8 b0 = *reinterpret_cast<const bf16x8*>(bs + rb + sp0);
      bf16x8 b1 = *reinterpret_cast<const bf16x8*>(bs + rb + sp1);
      f32x4 z = {0.f, 0.f, 0.f, 0.f};
      f32x4 tA = __builtin_amdgcn_mfma_f32_16x16x32_bf16(aA0, b0, z, 0, 0, 0);
      tA = __builtin_amdgcn_mfma_f32_16x16x32_bf16(aA1, b1, tA, 0, 0, 0);
      f32x4 tB = __builtin_amdgcn_mfma_f32_16x16x32_bf16(aB0, b0, z, 0, 0, 0);
      tB = __builtin_amdgcn_mfma_f32_16x16x32_bf16(aB1, b1, tB, 0, 0, 0);
      float cp = 0.f;
#pragma unroll
      for (int r = 0; r < 4; ++r) {
        float eA = EXPFN(tA[r]);
        float eB = EXPFN(tB[r]);
        accA[nf][r] += eA;
        accB[nf][r] += eB;
        cp += eA + eB;
      }
      colAcc[t][nf] = cp;   // this (t,nf) visited once
    }
  }

  // Row-sums: reduce the 16 lanes (same kh) holding one row; slot q.
#pragma unroll
  for (int r = 0; r < 4; ++r) {
    float vA = (accA[0][r] + accA[1][r]) + (accA[2][r] + accA[3][r]);
    float vB = (accB[0][r] + accB[1][r]) + (accB[2][r] + accB[3][r]);
    vA += __shfl_xor(vA, 1, 16);
    vA += __shfl_xor(vA, 2, 16);
    vA += __shfl_xor(vA, 4, 16);
    vA += __shfl_xor(vA, 8, 16);
    vB += __shfl_xor(vB, 1, 16);
    vB += __shfl_xor(vB, 2, 16);
    vB += __shfl_xor(vB, 4, 16);
    vB += __shfl_xor(vB, 8, 16);
    if (lrow == 0) {
      rowPart[(size_t)(i0 + kh * 4 + r) * NP + q] = vA;
      rowPart[(size_t)(i0 + 16 + kh * 4 + r) * NP + q] = vB;
    }
  }

  // Col-sums (off-diagonal only): exp(sim_ij)=exp(sim_ji) feeds q-panel rows.
  if (p != q) {
#pragma unroll
    for (int t = 0; t < 2; ++t)
#pragma unroll
      for (int nf = 0; nf < 4; ++nf) {
        float c = colAcc[t][nf];
        c += __shfl_xor(c, 16, 64);   // reduce across kh row-groups
        c += __shfl_xor(c, 32, 64);
        if (kh == 0) colRed[wave][t * 64 + nf * 16 + lrow] = c;
      }
    __syncthreads();                  // p!=q is block-uniform -> legal
    if (tid < 128) {
      float s = (colRed[0][tid] + colRed[1][tid]) +
                (colRed[2][tid] + colRed[3][tid]);
      rowPart[(size_t)(q0 + tid) * NP + p] = s;
    }
  }
}

// ---------------------------------------------------------------------------
// Kernel F1: per-block partials; F2: one wave reduces the 64 partials.
// ---------------------------------------------------------------------------
__global__ __launch_bounds__(256) void finpart_kernel(
    const u16* __restrict__ Gb, const float* __restrict__ rowPart,
    float* __restrict__ partA, float* __restrict__ partB) {
  __shared__ float sA[256];
  __shared__ float sB[256];
  const int tid = threadIdx.x, b = blockIdx.x;

  float logAcc = 0.f;
  if (tid < 128) {
    const int row = b * 128 + tid;
    const float4* rp = reinterpret_cast<const float4*>(rowPart + (size_t)row * NP);
    float s = 0.f;
#pragma unroll
    for (int c = 0; c < NP / 4; ++c) {
      float4 v = rp[c];
      s += (v.x + v.y) + (v.z + v.w);
    }
    logAcc = logf(s - EXP10);
  }
  float cross = 0.f;
  if (tid < 64) {
    const int u = b * 64 + tid;
    const unsigned* r0 = reinterpret_cast<const unsigned*>(Gb + (size_t)u * CDIM);
    const unsigned* r1 =
        reinterpret_cast<const unsigned*>(Gb + (size_t)(u + NLOC) * CDIM);
#pragma unroll
    for (int c = 0; c < 32; ++c) {
      unsigned a = r0[c], bb = r1[c];
      cross += bf2f(a & 0xffffu) * bf2f(bb & 0xffffu) + bf2f(a >> 16) * bf2f(bb >> 16);
    }
  }
  sA[tid] = logAcc;
  sB[tid] = cross;
  __syncthreads();
  for (int s = 128; s > 0; s >>= 1) {
    if (tid < s) { sA[tid] += sA[tid + s]; sB[tid] += sB[tid + s]; }
    __syncthreads();
  }
  if (tid == 0) { partA[b] = sA[0]; partB[b] = sB[0]; }
}

__global__ __launch_bounds__(64) void fin2_kernel(
    const float* __restrict__ partA, const float* __restrict__ partB,
    float* __restrict__ out) {
  const int l = threadIdx.x;
  float a = partA[l];
  float c = partB[l];
#pragma unroll
  for (int s = 1; s < 64; s <<= 1) {
    a += __shfl_xor(a, s, 64);
    c += __shfl_xor(c, s, 64);
  }
  if (l == 0) out[0] = (a - 2.0f * TINV * c) / (float)NROW;
}

// ---------------------------------------------------------------------------
extern "C" void kernel_launch(void* const* d_in, const int* in_sizes, int n_in,
                              void* d_out, int out_size, void* d_ws, size_t ws_size,
                              hipStream_t stream) {
  const float* emb0 = (const float*)d_in[0];
  const float* emb1 = (const float*)d_in[1];
  const float* loc0 = (const float*)d_in[2];
  const float* loc1 = (const float*)d_in[3];
  float* out = (float*)d_out;
  char* ws = (char*)d_ws;

  // rowPart is now [8192][64] f32 = 2 MB
  const size_t NEED = (16ull << 20) + (2ull << 20) + (2ull << 20) + (8ull << 10);
  u16 *Ga, *Gb;
  float *rowPart, *partA, *partB;

  if (ws_size >= NEED) {
    u16* embT0 = (u16*)(ws);
    u16* embT1 = (u16*)(ws + (8ull << 20));
    Ga = (u16*)(ws + (16ull << 20));
    Gb = (u16*)(ws + (17ull << 20));
    rowPart = (float*)(ws + (18ull << 20));
    partA = (float*)(ws + (20ull << 20));
    partB = partA + 64;

    dim3 tg(HW2 / 64, 2);
    transpose_kernel<<<tg, 256, 0, stream>>>(emb0, emb1, embT0, embT1);
    gather2_kernel<<<(NROW * 8) / 256, 256, 0, stream>>>(embT0, embT1, loc0, loc1,
                                                         Ga, Gb);
  } else {
    Ga = (u16*)ws;
    Gb = Ga + (size_t)NROW * CDIM;
    rowPart = (float*)(Gb + (size_t)NROW * CDIM);
    partA = rowPart + (size_t)NROW * NP;
    partB = partA + 64;
    gather_kernel<<<(NROW * CDIM) / 256, 256, 0, stream>>>(emb0, emb1, loc0, loc1,
                                                           Ga, Gb);
  }

  simsum_tri_kernel<<<NPAIR, 256, 0, stream>>>(Ga, Gb, rowPart);
  finpart_kernel<<<64, 256, 0, stream>>>(Gb, rowPart, partA, partB);
  fin2_kernel<<<1, 64, 0, stream>>>(partA, partB, out);
}